// Round 4
// baseline (309.156 us; speedup 1.0000x reference)
//
#include <hip/hip_runtime.h>
#include <hip/hip_bf16.h>
#include <hip/hip_fp16.h>

#define IN_DIM 128
#define HID 8
#define RW 128          // node range width
#define MAXR 1024       // max ranges
#define CCH 512         // edge chunks for count/scatter

// ---------------- pass1: per-chunk range histograms (int4-vectorized) ----------------
__global__ __launch_bounds__(256) void pass1_count(const int* __restrict__ src, const int* __restrict__ dst,
        int* __restrict__ cnt_d, int* __restrict__ cnt_s, int E, int R, int chunk) {
    __shared__ int cd[MAXR], cs[MAXR];
    int t = threadIdx.x, c = blockIdx.x;
    for (int i = t; i < R; i += 256) { cd[i] = 0; cs[i] = 0; }
    __syncthreads();
    int lo = c * chunk, hi = min(lo + chunk, E);
    if (lo < hi) {
        const int4* s4 = reinterpret_cast<const int4*>(src);
        const int4* d4 = reinterpret_cast<const int4*>(dst);
        int q0 = lo >> 2, q1 = hi >> 2;
        for (int q = q0 + t; q < q1; q += 256) {
            int4 d = d4[q], s = s4[q];
            atomicAdd(&cd[d.x >> 7], 1); atomicAdd(&cd[d.y >> 7], 1);
            atomicAdd(&cd[d.z >> 7], 1); atomicAdd(&cd[d.w >> 7], 1);
            atomicAdd(&cs[s.x >> 7], 1); atomicAdd(&cs[s.y >> 7], 1);
            atomicAdd(&cs[s.z >> 7], 1); atomicAdd(&cs[s.w >> 7], 1);
        }
        for (int i = (q1 << 2) + t; i < hi; i += 256) {
            atomicAdd(&cd[dst[i] >> 7], 1);
            atomicAdd(&cs[src[i] >> 7], 1);
        }
    }
    __syncthreads();
    for (int i = t; i < R; i += 256) {
        cnt_d[(size_t)c * R + i] = cd[i];
        cnt_s[(size_t)c * R + i] = cs[i];
    }
}

// ---------------- scan1: per-range exclusive scan over chunks + totals ----------------
__global__ __launch_bounds__(256) void scan1_kernel(int* __restrict__ cnt_d, int* __restrict__ cnt_s,
        int* __restrict__ tot_d, int* __restrict__ tot_s, int R) {
    int r = blockIdx.x;
    int* cnt = blockIdx.y ? cnt_s : cnt_d;
    int* tot = blockIdx.y ? tot_s : tot_d;
    __shared__ int sh[256];
    int t = threadIdx.x;
    int e0 = cnt[(size_t)(2 * t) * R + r];
    int e1 = cnt[(size_t)(2 * t + 1) * R + r];
    int s = e0 + e1;
    sh[t] = s;
    __syncthreads();
    for (int off = 1; off < 256; off <<= 1) {
        int v = (t >= off) ? sh[t - off] : 0;
        __syncthreads();
        sh[t] += v;
        __syncthreads();
    }
    int exc = sh[t] - s;
    cnt[(size_t)(2 * t) * R + r] = exc;
    cnt[(size_t)(2 * t + 1) * R + r] = exc + e0;
    if (t == 255) tot[r] = sh[255];
}

// ---------------- scan2: exclusive scan of range totals -> bucket bases ----------------
__global__ __launch_bounds__(256) void scan2_kernel(const int* __restrict__ tot_d, const int* __restrict__ tot_s,
        int* __restrict__ base_d, int* __restrict__ base_s, int R) {
    const int* tot = blockIdx.x ? tot_s : tot_d;
    int* base = blockIdx.x ? base_s : base_d;
    __shared__ int sh[256];
    int t = threadIdx.x;
    int K = (R + 255) / 256;
    int vals[4];
    int s = 0;
    for (int k = 0; k < K; ++k) {
        int i = t * K + k;
        int v = (i < R) ? tot[i] : 0;
        vals[k] = v; s += v;
    }
    sh[t] = s;
    __syncthreads();
    for (int off = 1; off < 256; off <<= 1) {
        int v = (t >= off) ? sh[t - off] : 0;
        __syncthreads();
        sh[t] += v;
        __syncthreads();
    }
    int exc = sh[t] - s;
    for (int k = 0; k < K; ++k) {
        int i = t * K + k;
        if (i < R) base[i] = exc;
        exc += vals[k];
    }
    if (t == 255) base[R] = sh[255];
}

// ---------------- scatter: bucket edges by dst range (packed) + src locals (bytes) ----------------
__global__ __launch_bounds__(256) void scatter_kernel(const int* __restrict__ src, const int* __restrict__ dst,
        const int* __restrict__ cnt_d, const int* __restrict__ cnt_s,
        const int* __restrict__ base_d, const int* __restrict__ base_s,
        unsigned int* __restrict__ bucket_d, unsigned char* __restrict__ bucket_s,
        int E, int R, int chunk) {
    __shared__ int od[MAXR], os[MAXR];
    int t = threadIdx.x, c = blockIdx.x;
    for (int i = t; i < R; i += 256) {
        od[i] = base_d[i] + cnt_d[(size_t)c * R + i];
        os[i] = base_s[i] + cnt_s[(size_t)c * R + i];
    }
    __syncthreads();
    int lo = c * chunk, hi = min(lo + chunk, E);
    if (lo >= hi) return;
    const int4* s4 = reinterpret_cast<const int4*>(src);
    const int4* d4 = reinterpret_cast<const int4*>(dst);
    int q0 = lo >> 2, q1 = hi >> 2;
    for (int q = q0 + t; q < q1; q += 256) {
        int4 d = d4[q], s = s4[q];
        int p;
        p = atomicAdd(&od[d.x >> 7], 1); bucket_d[p] = ((unsigned)s.x << 7) | (unsigned)(d.x & 127);
        p = atomicAdd(&od[d.y >> 7], 1); bucket_d[p] = ((unsigned)s.y << 7) | (unsigned)(d.y & 127);
        p = atomicAdd(&od[d.z >> 7], 1); bucket_d[p] = ((unsigned)s.z << 7) | (unsigned)(d.z & 127);
        p = atomicAdd(&od[d.w >> 7], 1); bucket_d[p] = ((unsigned)s.w << 7) | (unsigned)(d.w & 127);
        p = atomicAdd(&os[s.x >> 7], 1); bucket_s[p] = (unsigned char)(s.x & 127);
        p = atomicAdd(&os[s.y >> 7], 1); bucket_s[p] = (unsigned char)(s.y & 127);
        p = atomicAdd(&os[s.z >> 7], 1); bucket_s[p] = (unsigned char)(s.z & 127);
        p = atomicAdd(&os[s.w >> 7], 1); bucket_s[p] = (unsigned char)(s.w & 127);
    }
    for (int i = (q1 << 2) + t; i < hi; i += 256) {
        int s = src[i], d = dst[i];
        int pd = atomicAdd(&od[d >> 7], 1);
        bucket_d[pd] = ((unsigned)s << 7) | (unsigned)(d & 127);
        int ps = atomicAdd(&os[s >> 7], 1);
        bucket_s[ps] = (unsigned char)(s & 127);
    }
}

// ---------------- deg_out: per-range count of src locals (4B reads) ----------------
__global__ __launch_bounds__(256) void degout_kernel(const unsigned char* __restrict__ bucket_s,
        const int* __restrict__ base_s, float* __restrict__ deg_out, int N) {
    __shared__ int cnt[RW];
    int r = blockIdx.x, t = threadIdx.x;
    if (t < RW) cnt[t] = 0;
    __syncthreads();
    int lo = base_s[r], hi = base_s[r + 1];
    int a0 = min((lo + 3) & ~3, hi), a1 = max(hi & ~3, a0);
    for (int i = lo + t; i < a0; i += 256) atomicAdd(&cnt[bucket_s[i]], 1);
    const unsigned* w4 = reinterpret_cast<const unsigned*>(bucket_s);
    for (int q = (a0 >> 2) + t; q < (a1 >> 2); q += 256) {
        unsigned w = w4[q];
        atomicAdd(&cnt[w & 255], 1);
        atomicAdd(&cnt[(w >> 8) & 255], 1);
        atomicAdd(&cnt[(w >> 16) & 255], 1);
        atomicAdd(&cnt[w >> 24], 1);
    }
    for (int i = a1 + t; i < hi; i += 256) atomicAdd(&cnt[bucket_s[i]], 1);
    __syncthreads();
    if (t < RW) {
        int node = r * RW + t;
        if (node < N) deg_out[node] = (float)cnt[t];
    }
}

// ---------------- conv1: h = (x * norm_out) @ W1, packed to f16x8 (16B/node) ----------------
__global__ __launch_bounds__(256) void conv1_kernel(
        const float* __restrict__ x, const float* __restrict__ W1,
        const float* __restrict__ deg_out, uint4* __restrict__ h4, int N) {
    __shared__ float wt[HID * 132];
    int t = threadIdx.x;
    for (int i = t; i < IN_DIM * HID; i += 256) {
        int k = i >> 3, j = i & 7;
        wt[j * 132 + k] = W1[i];
    }
    __syncthreads();
    int grp = t >> 3, lane = t & 7;
    int node = blockIdx.x * 32 + grp;
    if (node >= N) return;
    const float4* xp = reinterpret_cast<const float4*>(x + (size_t)node * IN_DIM);
    float4 xv[4];
    #pragma unroll
    for (int m = 0; m < 4; ++m) xv[m] = xp[lane + m * 8];
    float acc[HID];
    #pragma unroll
    for (int j = 0; j < HID; ++j) acc[j] = 0.f;
    #pragma unroll
    for (int j = 0; j < HID; ++j) {
        #pragma unroll
        for (int m = 0; m < 4; ++m) {
            float4 wv = *reinterpret_cast<const float4*>(&wt[j * 132 + lane * 4 + m * 32]);
            acc[j] += xv[m].x * wv.x + xv[m].y * wv.y + xv[m].z * wv.z + xv[m].w * wv.w;
        }
    }
    #pragma unroll
    for (int off = 1; off < 8; off <<= 1) {
        #pragma unroll
        for (int j = 0; j < HID; ++j) acc[j] += __shfl_xor(acc[j], off, 64);
    }
    if (lane == 0) {
        float nrm = rsqrtf(fmaxf(deg_out[node], 1.0f));
        __half2 p0 = __floats2half2_rn(acc[0] * nrm, acc[1] * nrm);
        __half2 p1 = __floats2half2_rn(acc[2] * nrm, acc[3] * nrm);
        __half2 p2 = __floats2half2_rn(acc[4] * nrm, acc[5] * nrm);
        __half2 p3 = __floats2half2_rn(acc[6] * nrm, acc[7] * nrm);
        uint4 o;
        o.x = *reinterpret_cast<unsigned*>(&p0);
        o.y = *reinterpret_cast<unsigned*>(&p1);
        o.z = *reinterpret_cast<unsigned*>(&p2);
        o.w = *reinterpret_cast<unsigned*>(&p3);
        h4[node] = o;
    }
}

// ---------------- agg1: one 512-thread block per range, fused finalize -> h2, deg_in ----------------
__device__ __forceinline__ void addEdge1(float* tile, int* cnt, unsigned p, uint4 g) {
    int l = p & 127;
    __half2 q0 = *reinterpret_cast<__half2*>(&g.x);
    __half2 q1 = *reinterpret_cast<__half2*>(&g.y);
    __half2 q2 = *reinterpret_cast<__half2*>(&g.z);
    __half2 q3 = *reinterpret_cast<__half2*>(&g.w);
    float2 f0 = __half22float2(q0), f1 = __half22float2(q1);
    float2 f2 = __half22float2(q2), f3 = __half22float2(q3);
    atomicAdd(&cnt[l], 1);
    atomicAdd(&tile[0 * RW + l], f0.x);
    atomicAdd(&tile[1 * RW + l], f0.y);
    atomicAdd(&tile[2 * RW + l], f1.x);
    atomicAdd(&tile[3 * RW + l], f1.y);
    atomicAdd(&tile[4 * RW + l], f2.x);
    atomicAdd(&tile[5 * RW + l], f2.y);
    atomicAdd(&tile[6 * RW + l], f3.x);
    atomicAdd(&tile[7 * RW + l], f3.y);
}

__global__ __launch_bounds__(512) void agg1_kernel(const unsigned int* __restrict__ bucket_d,
        const int* __restrict__ base_d, const uint4* __restrict__ h4,
        const float* __restrict__ deg_out, const float* __restrict__ b1, const float* __restrict__ W2,
        float* __restrict__ h2, float* __restrict__ deg_in, int N) {
    __shared__ float tile[HID * RW];
    __shared__ int cnt[RW];
    int r = blockIdx.x, t = threadIdx.x;
    for (int i = t; i < HID * RW; i += 512) tile[i] = 0.f;
    if (t < RW) cnt[t] = 0;
    __syncthreads();
    int lo = base_d[r], hi = base_d[r + 1];
    int i = lo + t;
    for (; i + 1536 < hi; i += 2048) {
        unsigned p0 = bucket_d[i], p1 = bucket_d[i + 512], p2 = bucket_d[i + 1024], p3 = bucket_d[i + 1536];
        uint4 g0 = h4[p0 >> 7], g1 = h4[p1 >> 7], g2 = h4[p2 >> 7], g3 = h4[p3 >> 7];
        addEdge1(tile, cnt, p0, g0);
        addEdge1(tile, cnt, p1, g1);
        addEdge1(tile, cnt, p2, g2);
        addEdge1(tile, cnt, p3, g3);
    }
    for (; i < hi; i += 512) {
        unsigned p = bucket_d[i];
        uint4 g = h4[p >> 7];
        addEdge1(tile, cnt, p, g);
    }
    __syncthreads();
    if (t < RW) {
        int node = r * RW + t;
        if (node < N) {
            float din = (float)cnt[t];
            deg_in[node] = din;
            float nin = rsqrtf(fmaxf(din, 1.f));
            float nout = rsqrtf(fmaxf(deg_out[node], 1.f));
            float dot = 0.f;
            #pragma unroll
            for (int j = 0; j < HID; ++j) {
                float y = fmaxf(tile[j * RW + t] * nin + b1[j], 0.f);
                dot += y * W2[j];
            }
            h2[node] = dot * nout;
        }
    }
}

// ---------------- agg2: one 512-thread block per range, fused final output ----------------
__global__ __launch_bounds__(512) void agg2_kernel(const unsigned int* __restrict__ bucket_d,
        const int* __restrict__ base_d, const float* __restrict__ h2,
        const float* __restrict__ deg_in, const float* __restrict__ b2,
        float* __restrict__ out, int N) {
    __shared__ float tile[RW];
    int r = blockIdx.x, t = threadIdx.x;
    if (t < RW) tile[t] = 0.f;
    __syncthreads();
    int lo = base_d[r], hi = base_d[r + 1];
    int i = lo + t;
    for (; i + 1536 < hi; i += 2048) {
        unsigned p0 = bucket_d[i], p1 = bucket_d[i + 512], p2 = bucket_d[i + 1024], p3 = bucket_d[i + 1536];
        float v0 = h2[p0 >> 7], v1 = h2[p1 >> 7], v2 = h2[p2 >> 7], v3 = h2[p3 >> 7];
        atomicAdd(&tile[p0 & 127], v0);
        atomicAdd(&tile[p1 & 127], v1);
        atomicAdd(&tile[p2 & 127], v2);
        atomicAdd(&tile[p3 & 127], v3);
    }
    for (; i < hi; i += 512) {
        unsigned p = bucket_d[i];
        atomicAdd(&tile[p & 127], h2[p >> 7]);
    }
    __syncthreads();
    if (t < RW) {
        int node = r * RW + t;
        if (node < N) out[node] = tile[t] * rsqrtf(fmaxf(deg_in[node], 1.f)) + b2[0];
    }
}

extern "C" void kernel_launch(void* const* d_in, const int* in_sizes, int n_in,
                              void* d_out, int out_size, void* d_ws, size_t ws_size,
                              hipStream_t stream) {
    const float* x  = (const float*)d_in[0];
    const int* src  = (const int*)d_in[1];
    const int* dst  = (const int*)d_in[2];
    const float* W1 = (const float*)d_in[3];
    const float* b1 = (const float*)d_in[4];
    const float* W2 = (const float*)d_in[5];
    const float* b2 = (const float*)d_in[6];
    float* out = (float*)d_out;

    const int N = out_size;      // 100000
    const int E = in_sizes[1];   // 3200000
    const int R = (N + RW - 1) / RW;                    // 782
    const int chunk = (((E + CCH - 1) / CCH) + 3) & ~3; // multiple of 4 for int4 loads

    // workspace layout (all regions fully written before read; no memset needed)
    float* ws      = (float*)d_ws;
    float* deg_out = ws;                        // N
    float* deg_in  = deg_out + N;               // N
    float* h2      = deg_in + N;                // N
    int*   cnt_d   = (int*)(h2 + N);            // CCH*R
    int*   cnt_s   = cnt_d + (size_t)CCH * R;   // CCH*R
    int*   tot_d   = cnt_s + (size_t)CCH * R;   // R
    int*   tot_s   = tot_d + R;                 // R
    int*   base_d  = tot_s + R;                 // R+1
    int*   base_s  = base_d + R + 1;            // R+1
    uint4* h4      = (uint4*)(((uintptr_t)(base_s + R + 1) + 15) & ~(uintptr_t)15); // N uint4
    unsigned int*  bucket_d = (unsigned int*)(h4 + N);           // E
    unsigned char* bucket_s = (unsigned char*)(bucket_d + E);    // E bytes

    pass1_count<<<CCH, 256, 0, stream>>>(src, dst, cnt_d, cnt_s, E, R, chunk);
    scan1_kernel<<<dim3(R, 2), 256, 0, stream>>>(cnt_d, cnt_s, tot_d, tot_s, R);
    scan2_kernel<<<2, 256, 0, stream>>>(tot_d, tot_s, base_d, base_s, R);
    scatter_kernel<<<CCH, 256, 0, stream>>>(src, dst, cnt_d, cnt_s, base_d, base_s,
                                            bucket_d, bucket_s, E, R, chunk);
    degout_kernel<<<R, 256, 0, stream>>>(bucket_s, base_s, deg_out, N);
    conv1_kernel<<<(N + 31) / 32, 256, 0, stream>>>(x, W1, deg_out, h4, N);
    agg1_kernel<<<R, 512, 0, stream>>>(bucket_d, base_d, h4, deg_out, b1, W2, h2, deg_in, N);
    agg2_kernel<<<R, 512, 0, stream>>>(bucket_d, base_d, h2, deg_in, b2, out, N);
}